// Round 5
// baseline (357.459 us; speedup 1.0000x reference)
//
#include <hip/hip_runtime.h>
#include <hip/hip_bf16.h>
#include <cstddef>
#include <cstdint>

// Direct-conv reformulation of the Winograd reference (validated r1-r4):
// out[b,o,2i+p,2j+q] = bias[o] + sum_{c,y,x} xpad[b,c,2i-1+y,2j-1+x] * Keff[o,c,p,q,y,x]
// Implicit GEMM: M=65536 patches, N=384 (o*4+p*2+q), K=1024 (c*16+y*4+x), bf16 MFMA.
// Round 5: 4-channel chunks, TRIPLE-buffered LDS (37.2 KB -> exactly 4 blocks/CU
// resident for the 1024-block grid: no tail quantization, 16 waves/CU), steady
// vmcnt(6) with zero-page dummy stages for the tail chunks.

#define IHW 128
#define CIN 64
#define COUT 96

typedef __attribute__((ext_vector_type(8))) short short8_t;  // bf16x8 operand
typedef __attribute__((ext_vector_type(4))) float floatx4;   // f32 accum

__device__ __forceinline__ short bf16r(float f) {  // RNE fp32->bf16 (keff precompute)
  uint32_t u = __float_as_uint(f);
  uint32_t r = (u + 0x7FFFu + ((u >> 16) & 1u)) >> 16;
  return (short)r;
}

__device__ __forceinline__ short cvb(float f) {  // hw cvt path (v_cvt_pk-fusable)
  union { __hip_bfloat16 h; short s; } u;
  u.h = __float2bfloat16(f);
  return u.s;
}

// ---------------- Keff precompute + zero-page init ----------------
__global__ void keff_kernel(const float* __restrict__ w, short* __restrict__ keff,
                            float* __restrict__ zp) {
  if (blockIdx.x == 0) zp[threadIdx.x] = 0.f;  // 1 KB zero page
  int idx = blockIdx.x * 256 + threadIdx.x;
  if (idx >= COUT * CIN) return;
  int o = idx / CIN, c = idx % CIN;
  int g = o / 32;

  int perm[4] = {0, 1, 2, 3};
  if (g == 1) { perm[0] = 1; perm[1] = 0; }
  else if (g == 2) { perm[0] = 3; perm[3] = 0; }

  const float H[4][4] = {{1,1,1,1},{1,-1,1,-1},{1,1,-1,-1},{1,-1,-1,1}};
  float S[2][4];
#pragma unroll
  for (int p = 0; p < 2; ++p)
#pragma unroll
    for (int a = 0; a < 4; ++a) {
      bool pos = (g == 1) ? ((p == 0) ? true : (a < 2))
                          : ((p == 0) ? ((a & 1) == 0) : (a < 2));
      S[p][a] = pos ? 1.f : -1.f;
    }

  float wv[4][4];
#pragma unroll
  for (int a = 0; a < 4; ++a)
#pragma unroll
    for (int d = 0; d < 4; ++d) wv[a][d] = w[(o * CIN + c) * 16 + a * 4 + d];

  for (int p = 0; p < 2; ++p)
    for (int q = 0; q < 2; ++q) {
      int n = o * 4 + p * 2 + q;
      for (int y = 0; y < 4; ++y)
        for (int xx = 0; xx < 4; ++xx) {
          float s = 0.f;
#pragma unroll
          for (int a = 0; a < 4; ++a) {
            float ea = S[p][a] * H[a][perm[xx]];
#pragma unroll
            for (int d = 0; d < 4; ++d) s += ea * S[q][d] * H[d][perm[y]] * wv[a][d];
          }
          keff[n * 1024 + c * 16 + y * 4 + xx] = bf16r(s);
        }
    }
}

// ---------------- main conv kernel ----------------
// block: 256 threads = 4 waves (2 M x 2 N). Block tile M=128 patches, N=192.
// LDS: 3 buffers, each one 4-channel chunk = 12 row-pairs; pair p at dword p*257
// (257 % 32 == 1 -> l4-group pair offsets {0,1,3,4} split bank parity -> max 2-way, free).
#define PPITCH 257
#define NPAIRS 12
#define BUFDW (NPAIRS * PPITCH)  // 3084 dwords per buffer
#define GUARD 16
#define NCK 16

__global__ __launch_bounds__(256, 4) void conv_mfma(const float* __restrict__ x,
                                                    const short* __restrict__ keff,
                                                    const float* __restrict__ bias,
                                                    const float* __restrict__ zp,
                                                    float* __restrict__ out) {
  __shared__ float lds[GUARD + 3 * BUFDW + GUARD];  // 37,328 B -> 4 blocks/CU

  const int tid = threadIdx.x;
  const int lane = tid & 63;
  const int wid = tid >> 6;
  const int wavem = wid >> 1;
  const int wn = wid & 1;
  const int l15 = lane & 15;
  const int l4 = lane >> 4;

  // XCD-aware decomposition: both nblk of a tile land on the same XCD (id & 7).
  const int hw = blockIdx.x;               // 0..1023
  const int xcd = hw & 7;
  const int j = hw >> 3;                   // 0..127
  const int tile = (xcd << 6) | (j >> 1);  // 0..511
  const int nblk = j & 1;
  const int b = tile >> 5;
  const int ib = tile & 31;
  const int gy0 = ib * 4 - 1;

  const float* xb = x + (size_t)b * CIN * IHW * IHW;

  // staging: wave wid stages channel c_loc = wid of each chunk; s = row-pair 0..2
  const float* sbase[3];
  bool svalid[3];
#pragma unroll
  for (int s = 0; s < 3; ++s) {
    const int trow = 2 * s + (lane >> 5);
    const int gy = gy0 + trow;
    const bool v = (unsigned)gy < (unsigned)IHW;
    sbase[s] = xb + ((size_t)wid * IHW + (v ? gy : 0)) * IHW + (lane & 31) * 4;
    svalid[s] = v;
  }

// stage chunk ckv (4 channels) into buffer bufsel; dummy (zero-page) if ckv >= NCK
#define STAGE(bufsel, ckv)                                                         \
  {                                                                                \
    _Pragma("unroll") for (int s = 0; s < 3; ++s) {                                \
      const float* src = ((ckv) < NCK && svalid[s])                                \
                             ? sbase[s] + (size_t)(ckv) * (4 * IHW * IHW)          \
                             : zp;                                                 \
      __builtin_amdgcn_global_load_lds(                                            \
          (const __attribute__((address_space(1))) void*)src,                      \
          (__attribute__((address_space(3))) void*)                                \
              &lds[GUARD + (bufsel) * BUFDW + (wid * 3 + s) * PPITCH],             \
          16, 0, 0);                                                               \
    }                                                                              \
  }

  floatx4 acc[4][6];
#pragma unroll
  for (int i = 0; i < 4; ++i)
#pragma unroll
    for (int j2 = 0; j2 < 6; ++j2) acc[i][j2] = (floatx4){0.f, 0.f, 0.f, 0.f};

  const short* kbase = keff + ((size_t)(nblk * 192 + wn * 96 + l15)) * 1024 + l4 * 8;

  float biasr[6];
#pragma unroll
  for (int nf = 0; nf < 6; ++nf) biasr[nf] = bias[nblk * 48 + wn * 24 + nf * 4 + l4];

  // prologue: stage chunks 0..2, prime A-frag pipeline
  STAGE(0, 0);
  STAGE(1, 1);
  STAGE(2, 2);
  short8_t afc[6], afn[6];
#pragma unroll
  for (int nf = 0; nf < 6; ++nf)
    afc[nf] = *reinterpret_cast<const short8_t*>(kbase + nf * 16 * 1024);

  for (int ck = 0; ck < NCK; ++ck) {
    // wait this chunk's 3 loads (2 newer stages = 6 outstanding stay in flight)
    asm volatile("s_waitcnt vmcnt(6)" ::: "memory");
    __builtin_amdgcn_s_barrier();
    __builtin_amdgcn_sched_barrier(0);

    const int bsel = ck % 3;
    const int bb = GUARD + bsel * BUFDW;
#pragma unroll
    for (int kk = 0; kk < 2; ++kk) {
      const int step = ck * 2 + kk;
      const int nstep = (step + 1) & 31;
#pragma unroll
      for (int nf = 0; nf < 6; ++nf)
        afn[nf] = *reinterpret_cast<const short8_t*>(kbase + nf * 16 * 1024 + nstep * 32);

      // pair index: {c_loc = 2*kk + (l4>>1)} * 3 + wavem + (l4&1)
      const int p = (2 * kk + (l4 >> 1)) * 3 + wavem + (l4 & 1);
      const int rb = bb + p * PPITCH;

#pragma unroll
      for (int mf = 0; mf < 4; ++mf) {
        const int cb = rb + 2 * (mf * 16 + l15);
        float f0 = lds[cb - 1], f1 = lds[cb], f2 = lds[cb + 1], f3 = lds[cb + 2];
        float g0 = lds[cb + 127], g1 = lds[cb + 128], g2 = lds[cb + 129], g3 = lds[cb + 130];
        if (mf == 0 && l15 == 0) { f0 = 0.f; g0 = 0.f; }   // gx = -1
        if (mf == 3 && l15 == 15) { f3 = 0.f; g3 = 0.f; }  // gx = 128
        short8_t bfrag;
        bfrag[0] = cvb(f0); bfrag[1] = cvb(f1); bfrag[2] = cvb(f2); bfrag[3] = cvb(f3);
        bfrag[4] = cvb(g0); bfrag[5] = cvb(g1); bfrag[6] = cvb(g2); bfrag[7] = cvb(g3);
#pragma unroll
        for (int nf = 0; nf < 6; ++nf)
          acc[mf][nf] = __builtin_amdgcn_mfma_f32_16x16x32_bf16(afc[nf], bfrag,
                                                                acc[mf][nf], 0, 0, 0);
      }
#pragma unroll
      for (int nf = 0; nf < 6; ++nf) afc[nf] = afn[nf];
    }

    // all waves done reading buffer bsel -> safe to restage it for chunk ck+3
    __builtin_amdgcn_s_barrier();
    __builtin_amdgcn_sched_barrier(0);
    STAGE(bsel, ck + 3);
  }

  // epilogue (unchanged, validated r2): D row = n, D col = patch j
  const int i_row = ib * 2 + wavem;
  const int orow0 = 2 * i_row;
#pragma unroll
  for (int nf = 0; nf < 6; ++nf) {
    const int o = nblk * 48 + wn * 24 + nf * 4 + l4;
    const float bv = biasr[nf];
    float* obase = out + ((size_t)(b * COUT + o) * IHW + orow0) * IHW;
#pragma unroll
    for (int mf = 0; mf < 4; ++mf) {
      const int col = 2 * (mf * 16 + l15);
      float2 s0 = make_float2(acc[mf][nf][0] + bv, acc[mf][nf][1] + bv);
      float2 s1 = make_float2(acc[mf][nf][2] + bv, acc[mf][nf][3] + bv);
      *reinterpret_cast<float2*>(obase + col) = s0;
      *reinterpret_cast<float2*>(obase + IHW + col) = s1;
    }
  }
#undef STAGE
}

extern "C" void kernel_launch(void* const* d_in, const int* in_sizes, int n_in,
                              void* d_out, int out_size, void* d_ws, size_t ws_size,
                              hipStream_t stream) {
  const float* x = (const float*)d_in[0];
  const float* w = (const float*)d_in[1];
  const float* bias = (const float*)d_in[2];
  float* out = (float*)d_out;
  short* keff = (short*)d_ws;                              // 786432 B
  float* zp = (float*)((char*)d_ws + 786432);              // 1 KB zero page

  hipLaunchKernelGGL(keff_kernel, dim3(24), dim3(256), 0, stream, w, keff, zp);
  hipLaunchKernelGGL(conv_mfma, dim3(1024), dim3(256), 0, stream, x, keff, bias, zp, out);
}

// Round 6
// 126.372 us; speedup vs baseline: 2.8286x; 2.8286x over previous
//
#include <hip/hip_runtime.h>
#include <hip/hip_bf16.h>
#include <cstddef>
#include <cstdint>

// Direct-conv reformulation of the Winograd reference (validated r1-r4):
// out[b,o,2i+p,2j+q] = bias[o] + sum_{c,y,x} xpad[b,c,2i-1+y,2j-1+x] * Keff[o,c,p,q,y,x]
// Implicit GEMM: M=65536 patches, N=384 (o*4+p*2+q), K=1024 (c*16+y*4+x), bf16 MFMA.
// Round 6: N split into quarters (N=96/block, grid 2048) to cut per-wave regs
// (acc 96->48, af 48->24) -> ~110 regs -> 4 waves/SIMD, 4 blocks/CU, no forced
// launch bounds (r5's spill lesson). 4-ch chunks double-buffered (24.9 KB LDS),
// steady vmcnt(3), pair-gap pitch (bank-conflict-free), 4-way XCD tile pairing.

#define IHW 128
#define CIN 64
#define COUT 96

typedef __attribute__((ext_vector_type(8))) short short8_t;  // bf16x8 operand
typedef __attribute__((ext_vector_type(4))) float floatx4;   // f32 accum

__device__ __forceinline__ short bf16r(float f) {  // RNE fp32->bf16 (keff precompute)
  uint32_t u = __float_as_uint(f);
  uint32_t r = (u + 0x7FFFu + ((u >> 16) & 1u)) >> 16;
  return (short)r;
}

__device__ __forceinline__ short cvb(float f) {  // hw cvt path (v_cvt_pk-fusable)
  union { __hip_bfloat16 h; short s; } u;
  u.h = __float2bfloat16(f);
  return u.s;
}

// ---------------- Keff precompute + zero-page init ----------------
__global__ void keff_kernel(const float* __restrict__ w, short* __restrict__ keff,
                            float* __restrict__ zp) {
  if (blockIdx.x == 0) zp[threadIdx.x] = 0.f;  // 1 KB zero page
  int idx = blockIdx.x * 256 + threadIdx.x;
  if (idx >= COUT * CIN) return;
  int o = idx / CIN, c = idx % CIN;
  int g = o / 32;

  int perm[4] = {0, 1, 2, 3};
  if (g == 1) { perm[0] = 1; perm[1] = 0; }
  else if (g == 2) { perm[0] = 3; perm[3] = 0; }

  const float H[4][4] = {{1,1,1,1},{1,-1,1,-1},{1,1,-1,-1},{1,-1,-1,1}};
  float S[2][4];
#pragma unroll
  for (int p = 0; p < 2; ++p)
#pragma unroll
    for (int a = 0; a < 4; ++a) {
      bool pos = (g == 1) ? ((p == 0) ? true : (a < 2))
                          : ((p == 0) ? ((a & 1) == 0) : (a < 2));
      S[p][a] = pos ? 1.f : -1.f;
    }

  float wv[4][4];
#pragma unroll
  for (int a = 0; a < 4; ++a)
#pragma unroll
    for (int d = 0; d < 4; ++d) wv[a][d] = w[(o * CIN + c) * 16 + a * 4 + d];

  for (int p = 0; p < 2; ++p)
    for (int q = 0; q < 2; ++q) {
      int n = o * 4 + p * 2 + q;
      for (int y = 0; y < 4; ++y)
        for (int xx = 0; xx < 4; ++xx) {
          float s = 0.f;
#pragma unroll
          for (int a = 0; a < 4; ++a) {
            float ea = S[p][a] * H[a][perm[xx]];
#pragma unroll
            for (int d = 0; d < 4; ++d) s += ea * S[q][d] * H[d][perm[y]] * wv[a][d];
          }
          keff[n * 1024 + c * 16 + y * 4 + xx] = bf16r(s);
        }
    }
}

// ---------------- main conv kernel ----------------
// block: 256 threads = 4 waves (2 M x 2 N). Block tile M=128 patches, N=96.
// LDS: 2 buffers, each one 4-channel chunk = 12 row-pairs; pair p at dword p*257
// (257 % 32 == 1 -> l4-group pair offsets split bank parity -> max 2-way, free).
#define PPITCH 257
#define NPAIRS 12
#define BUFDW (NPAIRS * PPITCH)  // 3084 dwords per buffer
#define GUARD 16
#define NCK 16

__global__ __launch_bounds__(256) void conv_mfma(const float* __restrict__ x,
                                                 const short* __restrict__ keff,
                                                 const float* __restrict__ bias,
                                                 const float* __restrict__ zp,
                                                 float* __restrict__ out) {
  __shared__ float lds[GUARD + 2 * BUFDW + GUARD];  // 24,928 B -> LDS allows 6/CU

  const int tid = threadIdx.x;
  const int lane = tid & 63;
  const int wid = tid >> 6;
  const int wavem = wid >> 1;
  const int wn = wid & 1;
  const int l15 = lane & 15;
  const int l4 = lane >> 4;

  // XCD-aware decomposition: all 4 n-quarters of a tile land on one XCD (id & 7).
  const int hw = blockIdx.x;               // 0..2047
  const int xcd = hw & 7;
  const int jj = hw >> 3;                  // 0..255
  const int tile = (xcd << 6) | (jj >> 2); // 0..511
  const int nblk = jj & 3;                 // n-quarter 0..3
  const int b = tile >> 5;
  const int ib = tile & 31;
  const int gy0 = ib * 4 - 1;

  const float* xb = x + (size_t)b * CIN * IHW * IHW;

  // staging: wave wid stages channel c_loc = wid of each 4-ch chunk; s = pair 0..2
  const float* sbase[3];
  bool svalid[3];
#pragma unroll
  for (int s = 0; s < 3; ++s) {
    const int trow = 2 * s + (lane >> 5);
    const int gy = gy0 + trow;
    const bool v = (unsigned)gy < (unsigned)IHW;
    sbase[s] = xb + ((size_t)wid * IHW + (v ? gy : 0)) * IHW + (lane & 31) * 4;
    svalid[s] = v;
  }

// stage chunk ckv (4 channels) into buffer bufsel; dummy (zero-page) if ckv >= NCK
#define STAGE(bufsel, ckv)                                                         \
  {                                                                                \
    _Pragma("unroll") for (int s = 0; s < 3; ++s) {                                \
      const float* src = ((ckv) < NCK && svalid[s])                                \
                             ? sbase[s] + (size_t)(ckv) * (4 * IHW * IHW)          \
                             : zp;                                                 \
      __builtin_amdgcn_global_load_lds(                                            \
          (const __attribute__((address_space(1))) void*)src,                      \
          (__attribute__((address_space(3))) void*)                                \
              &lds[GUARD + (bufsel) * BUFDW + (wid * 3 + s) * PPITCH],             \
          16, 0, 0);                                                               \
    }                                                                              \
  }

  floatx4 acc[4][3];
#pragma unroll
  for (int i = 0; i < 4; ++i)
#pragma unroll
    for (int j2 = 0; j2 < 3; ++j2) acc[i][j2] = (floatx4){0.f, 0.f, 0.f, 0.f};

  // n = nblk*96 + wn*48 + nf*16 + l15
  const short* kbase = keff + ((size_t)(nblk * 96 + wn * 48 + l15)) * 1024 + l4 * 8;

  float biasr[3];
#pragma unroll
  for (int nf = 0; nf < 3; ++nf) biasr[nf] = bias[nblk * 24 + wn * 12 + nf * 4 + l4];

  // prologue: stage chunks 0,1; prime A-frag pipeline
  STAGE(0, 0);
  STAGE(1, 1);
  short8_t afc[3], afn[3];
#pragma unroll
  for (int nf = 0; nf < 3; ++nf)
    afc[nf] = *reinterpret_cast<const short8_t*>(kbase + nf * 16 * 1024);

  for (int ck = 0; ck < NCK; ++ck) {
    // current chunk's 3 loads done; next chunk's 3 stay in flight
    asm volatile("s_waitcnt vmcnt(3)" ::: "memory");
    __builtin_amdgcn_s_barrier();
    __builtin_amdgcn_sched_barrier(0);

    const int bsel = ck & 1;
    const int bb = GUARD + bsel * BUFDW;
#pragma unroll
    for (int kk = 0; kk < 2; ++kk) {
      const int step = ck * 2 + kk;
      const int nstep = (step + 1) & 31;
#pragma unroll
      for (int nf = 0; nf < 3; ++nf)
        afn[nf] = *reinterpret_cast<const short8_t*>(kbase + nf * 16 * 1024 + nstep * 32);

      // pair index: {c_loc = 2*kk + (l4>>1)} * 3 + wavem + (l4&1)
      const int p = (2 * kk + (l4 >> 1)) * 3 + wavem + (l4 & 1);
      const int rb = bb + p * PPITCH;

#pragma unroll
      for (int mf = 0; mf < 4; ++mf) {
        const int cb = rb + 2 * (mf * 16 + l15);
        float f0 = lds[cb - 1], f1 = lds[cb], f2 = lds[cb + 1], f3 = lds[cb + 2];
        float g0 = lds[cb + 127], g1 = lds[cb + 128], g2 = lds[cb + 129], g3 = lds[cb + 130];
        if (mf == 0 && l15 == 0) { f0 = 0.f; g0 = 0.f; }   // gx = -1
        if (mf == 3 && l15 == 15) { f3 = 0.f; g3 = 0.f; }  // gx = 128
        short8_t bfrag;
        bfrag[0] = cvb(f0); bfrag[1] = cvb(f1); bfrag[2] = cvb(f2); bfrag[3] = cvb(f3);
        bfrag[4] = cvb(g0); bfrag[5] = cvb(g1); bfrag[6] = cvb(g2); bfrag[7] = cvb(g3);
#pragma unroll
        for (int nf = 0; nf < 3; ++nf)
          acc[mf][nf] = __builtin_amdgcn_mfma_f32_16x16x32_bf16(afc[nf], bfrag,
                                                                acc[mf][nf], 0, 0, 0);
      }
#pragma unroll
      for (int nf = 0; nf < 3; ++nf) afc[nf] = afn[nf];
    }

    // all waves done reading buffer bsel -> safe to restage it for chunk ck+2
    __builtin_amdgcn_s_barrier();
    __builtin_amdgcn_sched_barrier(0);
    STAGE(bsel, ck + 2);
  }

  // epilogue (validated r2 mapping): o = nblk*24 + wn*12 + nf*4 + l4, pq = reg idx
  const int i_row = ib * 2 + wavem;
  const int orow0 = 2 * i_row;
#pragma unroll
  for (int nf = 0; nf < 3; ++nf) {
    const int o = nblk * 24 + wn * 12 + nf * 4 + l4;
    const float bv = biasr[nf];
    float* obase = out + ((size_t)(b * COUT + o) * IHW + orow0) * IHW;
#pragma unroll
    for (int mf = 0; mf < 4; ++mf) {
      const int col = 2 * (mf * 16 + l15);
      float2 s0 = make_float2(acc[mf][nf][0] + bv, acc[mf][nf][1] + bv);
      float2 s1 = make_float2(acc[mf][nf][2] + bv, acc[mf][nf][3] + bv);
      *reinterpret_cast<float2*>(obase + col) = s0;
      *reinterpret_cast<float2*>(obase + IHW + col) = s1;
    }
  }
#undef STAGE
}

extern "C" void kernel_launch(void* const* d_in, const int* in_sizes, int n_in,
                              void* d_out, int out_size, void* d_ws, size_t ws_size,
                              hipStream_t stream) {
  const float* x = (const float*)d_in[0];
  const float* w = (const float*)d_in[1];
  const float* bias = (const float*)d_in[2];
  float* out = (float*)d_out;
  short* keff = (short*)d_ws;                              // 786432 B
  float* zp = (float*)((char*)d_ws + 786432);              // 1 KB zero page

  hipLaunchKernelGGL(keff_kernel, dim3(24), dim3(256), 0, stream, w, keff, zp);
  hipLaunchKernelGGL(conv_mfma, dim3(2048), dim3(256), 0, stream, x, keff, bias, zp, out);
}